// Round 1
// baseline (3711.868 us; speedup 1.0000x reference)
//
#include <hip/hip_runtime.h>

#define N_NODES 50000

// ---------------- sparse side ----------------

__global__ void count_edges_k(const int* __restrict__ dst, int E, float* __restrict__ cnt) {
    int t = blockIdx.x * 256 + threadIdx.x;
    if (t < E) atomicAdd(&cnt[dst[t]], 1.0f);
}

__global__ void make_inv_k(float* __restrict__ cnt, int n) {
    int t = blockIdx.x * 256 + threadIdx.x;
    if (t < n) cnt[t] = 1.0f / fmaxf(cnt[t], 1.0f);
}

// one thread = (edge, 4 consecutive features); coalesced gather, 4 scalar atomics
__global__ void scatter_add_k(const int* __restrict__ src, const int* __restrict__ dst, int E,
                              const float* __restrict__ in, int sin,
                              float* __restrict__ agg, int sagg, int F4) {
    long long t = (long long)blockIdx.x * 256 + threadIdx.x;
    if (t >= (long long)E * F4) return;
    int e = (int)(t / F4);
    int c = (int)(t % F4) * 4;
    int s = src[e], d = dst[e];
    float4 v = *(const float4*)&in[(long long)s * sin + c];
    float* p = &agg[(long long)d * sagg + c];
    atomicAdd(p + 0, v.x);
    atomicAdd(p + 1, v.y);
    atomicAdd(p + 2, v.z);
    atomicAdd(p + 3, v.w);
}

// ---------------- dense side ----------------
// out[i, ocol+o] = relu( inv[i] * (A1[i,:K1] @ W1)[o] + (A2[i,:K2] @ W2)[o] + bias[o] )
// 256 threads; thread = (mg, og) computes a 4x4 (node x outfeat) micro-tile.
// LDS A tile row-major with LDA=68 pad (keeps float4-over-k reads <=2-way bank aliased).

template <int O, int TM>
__global__ __launch_bounds__(256) void sage_gemm_k(
    const float* __restrict__ A1, int s1, int K1, const float* __restrict__ W1,
    const float* __restrict__ A2, int s2, int K2, const float* __restrict__ W2,
    const float* __restrict__ bias, const float* __restrict__ inv,
    float* __restrict__ out, int so, int ocol)
{
    constexpr int OG = O / 4;        // out-feature groups of 4
    constexpr int MG = 256 / OG;     // node groups of 4
    static_assert(MG * 4 == TM, "tile mismatch");
    constexpr int LDA = 68;          // padded row stride in floats
    __shared__ float ldsA[TM * LDA];
    __shared__ float ldsW[64 * O];

    const int tid = threadIdx.x;
    const int og = tid % OG;
    const int mg = tid / OG;
    const int node0 = blockIdx.x * TM;

    float acc[4][4];
#pragma unroll
    for (int a = 0; a < 4; a++)
#pragma unroll
        for (int b = 0; b < 4; b++) acc[a][b] = 0.f;

#pragma unroll 1
    for (int phase = 0; phase < 2; ++phase) {
        const float* A = phase ? A2 : A1;
        const float* W = phase ? W2 : W1;
        const int K = phase ? K2 : K1;
        const int sA = phase ? s2 : s1;

        if (phase == 1 && K1 > 0) {
            // fold mean-normalization: (agg*inv) @ W == inv * (agg @ W)
#pragma unroll
            for (int mi = 0; mi < 4; mi++) {
                int node = node0 + 4 * mg + mi;
                float iv = (node < N_NODES) ? inv[node] : 0.f;
#pragma unroll
                for (int oi = 0; oi < 4; oi++) acc[mi][oi] *= iv;
            }
        }

#pragma unroll 1
        for (int k0 = 0; k0 < K; k0 += 64) {
            __syncthreads();
            // stage A tile: TM rows x 64 cols, coalesced float4 reads
#pragma unroll
            for (int i = tid; i < TM * 16; i += 256) {
                int m = i / 16, kc = i % 16;
                int node = node0 + m;
                float4 v = {0.f, 0.f, 0.f, 0.f};
                if (node < N_NODES)
                    v = *(const float4*)&A[(long long)node * sA + k0 + 4 * kc];
                *(float4*)&ldsA[m * LDA + 4 * kc] = v;
            }
            // stage W tile: 64 rows x O cols
#pragma unroll
            for (int i = tid; i < 16 * O; i += 256) {
                int kr = i / OG, oc = (i % OG) * 4;
                *(float4*)&ldsW[kr * O + oc] = *(const float4*)&W[(long long)(k0 + kr) * O + oc];
            }
            __syncthreads();

#pragma unroll 4
            for (int kq = 0; kq < 16; kq++) {
                float4 a0 = *(const float4*)&ldsA[(4 * mg + 0) * LDA + 4 * kq];
                float4 a1 = *(const float4*)&ldsA[(4 * mg + 1) * LDA + 4 * kq];
                float4 a2 = *(const float4*)&ldsA[(4 * mg + 2) * LDA + 4 * kq];
                float4 a3 = *(const float4*)&ldsA[(4 * mg + 3) * LDA + 4 * kq];
                float4 w0 = *(const float4*)&ldsW[(4 * kq + 0) * O + 4 * og];
                float4 w1 = *(const float4*)&ldsW[(4 * kq + 1) * O + 4 * og];
                float4 w2 = *(const float4*)&ldsW[(4 * kq + 2) * O + 4 * og];
                float4 w3 = *(const float4*)&ldsW[(4 * kq + 3) * O + 4 * og];

                float aa[4][4] = {{a0.x, a0.y, a0.z, a0.w},
                                  {a1.x, a1.y, a1.z, a1.w},
                                  {a2.x, a2.y, a2.z, a2.w},
                                  {a3.x, a3.y, a3.z, a3.w}};
                float ww[4][4] = {{w0.x, w0.y, w0.z, w0.w},
                                  {w1.x, w1.y, w1.z, w1.w},
                                  {w2.x, w2.y, w2.z, w2.w},
                                  {w3.x, w3.y, w3.z, w3.w}};
#pragma unroll
                for (int mi = 0; mi < 4; mi++)
#pragma unroll
                    for (int oi = 0; oi < 4; oi++)
#pragma unroll
                        for (int kj = 0; kj < 4; kj++)
                            acc[mi][oi] += aa[mi][kj] * ww[kj][oi];
            }
        }
    }

    // epilogue: bias + relu + store
#pragma unroll
    for (int mi = 0; mi < 4; mi++) {
        int node = node0 + 4 * mg + mi;
        if (node >= N_NODES) continue;
        float4 r;
        r.x = fmaxf(acc[mi][0] + bias[4 * og + 0], 0.f);
        r.y = fmaxf(acc[mi][1] + bias[4 * og + 1], 0.f);
        r.z = fmaxf(acc[mi][2] + bias[4 * og + 2], 0.f);
        r.w = fmaxf(acc[mi][3] + bias[4 * og + 3], 0.f);
        *(float4*)&out[(long long)node * so + ocol + 4 * og] = r;
    }
}

// ---------------- launch ----------------

extern "C" void kernel_launch(void* const* d_in, const int* in_sizes, int n_in,
                              void* d_out, int out_size, void* d_ws, size_t ws_size,
                              hipStream_t stream) {
    const float* x   = (const float*)d_in[0];
    const int*   ei  = (const int*)d_in[1];
    const float* Wp  = (const float*)d_in[2];
    const float* bp  = (const float*)d_in[3];
    const float* Wl1 = (const float*)d_in[4];
    const float* bl1 = (const float*)d_in[5];
    const float* Wr1 = (const float*)d_in[6];
    const float* Wl2 = (const float*)d_in[7];
    const float* bl2 = (const float*)d_in[8];
    const float* Wr2 = (const float*)d_in[9];
    const float* Wl3 = (const float*)d_in[10];
    const float* bl3 = (const float*)d_in[11];
    const float* Wr3 = (const float*)d_in[12];

    const int E = in_sizes[1] / 2;
    const int N = N_NODES;
    const int* src = ei;
    const int* dst = ei + E;

    // workspace layout (floats):
    // feats [N,256] = [x_p | h1 | h2], agg [N,256] = scatter of feats,
    // aggx [N,64] = scatter of x, inv [N]
    float* feats = (float*)d_ws;
    float* agg   = feats + (size_t)N * 256;
    float* aggx  = agg   + (size_t)N * 256;
    float* inv   = aggx  + (size_t)N * 64;

    hipMemsetAsync(inv,  0, (size_t)N * sizeof(float), stream);
    hipMemsetAsync(aggx, 0, (size_t)N * 64 * sizeof(float), stream);
    hipMemsetAsync(agg,  0, (size_t)N * 256 * sizeof(float), stream);

    count_edges_k<<<(E + 255) / 256, 256, 0, stream>>>(dst, E, inv);
    make_inv_k<<<(N + 255) / 256, 256, 0, stream>>>(inv, N);

    // x_p = relu(x @ Wp + bp) -> feats[:,0:64]
    sage_gemm_k<64, 64><<<(N + 63) / 64, 256, 0, stream>>>(
        nullptr, 0, 0, nullptr, x, 64, 64, Wp, bp, inv, feats, 256, 0);

    // aggx = scatter(x)  [N,64]
    {
        long long tot = (long long)E * 16;
        scatter_add_k<<<(int)((tot + 255) / 256), 256, 0, stream>>>(
            src, dst, E, x, 64, aggx, 64, 16);
    }
    // h1 = relu(inv*(aggx@Wl1) + x@Wr1 + bl1) -> feats[:,64:128]
    sage_gemm_k<64, 64><<<(N + 63) / 64, 256, 0, stream>>>(
        aggx, 64, 64, Wl1, x, 64, 64, Wr1, bl1, inv, feats, 256, 64);

    // agg[:,0:128] = scatter(feats[:,0:128])   (reused by layers 2 AND 3)
    {
        long long tot = (long long)E * 32;
        scatter_add_k<<<(int)((tot + 255) / 256), 256, 0, stream>>>(
            src, dst, E, feats, 256, agg, 256, 32);
    }
    // h2 = relu(inv*(agg[:,:128]@Wl2) + feats[:,:128]@Wr2 + bl2) -> feats[:,128:256]
    sage_gemm_k<128, 32><<<(N + 31) / 32, 256, 0, stream>>>(
        agg, 256, 128, Wl2, feats, 256, 128, Wr2, bl2, inv, feats, 256, 128);

    // agg[:,128:256] = scatter(feats[:,128:256])
    {
        long long tot = (long long)E * 32;
        scatter_add_k<<<(int)((tot + 255) / 256), 256, 0, stream>>>(
            src, dst, E, feats + 128, 256, agg + 128, 256, 32);
    }
    // h3 = relu(inv*(agg@Wl3) + feats@Wr3 + bl3) -> d_out [N,128]
    sage_gemm_k<128, 32><<<(N + 31) / 32, 256, 0, stream>>>(
        agg, 256, 256, Wl3, feats, 256, 256, Wr3, bl3, inv, (float*)d_out, 128, 0);
}

// Round 2
// 548.131 us; speedup vs baseline: 6.7719x; 6.7719x over previous
//
#include <hip/hip_runtime.h>

#define N_NODES 50000

// ---------------- CSR build ----------------

__global__ void count_edges_k(const int* __restrict__ dst, int E, int* __restrict__ cnt) {
    int t = blockIdx.x * 256 + threadIdx.x;
    if (t < E) atomicAdd(&cnt[dst[t]], 1);
}

__global__ void make_inv_k(const int* __restrict__ cnt, float* __restrict__ inv, int n) {
    int t = blockIdx.x * 256 + threadIdx.x;
    if (t < n) inv[t] = 1.0f / fmaxf((float)cnt[t], 1.0f);
}

// Hillis-Steele inclusive scan per 256-block
__global__ void scan1_k(const int* __restrict__ cnt, int n,
                        int* __restrict__ incl, int* __restrict__ bsum) {
    __shared__ int s[256];
    int t = threadIdx.x, i = blockIdx.x * 256 + t;
    s[t] = (i < n) ? cnt[i] : 0;
    __syncthreads();
#pragma unroll
    for (int off = 1; off < 256; off <<= 1) {
        int u = (t >= off) ? s[t - off] : 0;
        __syncthreads();
        s[t] += u;
        __syncthreads();
    }
    if (i < n) incl[i] = s[t];
    if (t == 255) bsum[blockIdx.x] = s[255];
}

// single-block exclusive scan of block sums (nb <= 256)
__global__ void scan2_k(int* __restrict__ bsum, int nb) {
    __shared__ int s[256];
    int t = threadIdx.x;
    s[t] = (t < nb) ? bsum[t] : 0;
    __syncthreads();
#pragma unroll
    for (int off = 1; off < 256; off <<= 1) {
        int u = (t >= off) ? s[t - off] : 0;
        __syncthreads();
        s[t] += u;
        __syncthreads();
    }
    int ex = (t == 0) ? 0 : s[t - 1];
    if (t < nb) bsum[t] = ex;
}

__global__ void scan3_k(const int* __restrict__ incl, const int* __restrict__ cnt,
                        const int* __restrict__ boff, int n, int E, int* __restrict__ row_ptr) {
    int i = blockIdx.x * 256 + threadIdx.x;
    if (i < n) row_ptr[i] = incl[i] - cnt[i] + boff[blockIdx.x];
    if (i == 0) row_ptr[n] = E;
}

__global__ void fill_csr_k(const int* __restrict__ src, const int* __restrict__ dst, int E,
                           const int* __restrict__ row_ptr, int* __restrict__ fillc,
                           int* __restrict__ csr) {
    int t = blockIdx.x * 256 + threadIdx.x;
    if (t < E) {
        int d = dst[t];
        int p = row_ptr[d] + atomicAdd(&fillc[d], 1);
        csr[p] = src[t];
    }
}

// ---------------- gather aggregation (sum; mean folded into GEMM via inv) -------
// one wave per node; lane l owns feature columns {l, l+64, ...}. csr/row_ptr
// accesses are wave-uniform -> scalar loads. Unroll-2 over edges for MLP.

template <int NV>
__global__ __launch_bounds__(256) void gather_k(const int* __restrict__ row_ptr,
                                                const int* __restrict__ csr,
                                                const float* __restrict__ in, int sin,
                                                float* __restrict__ out, int sout) {
    int node = blockIdx.x * 4 + (threadIdx.x >> 6);
    if (node >= N_NODES) return;
    int lane = threadIdx.x & 63;
    int b = row_ptr[node], e = row_ptr[node + 1];
    float acc[NV];
#pragma unroll
    for (int j = 0; j < NV; j++) acc[j] = 0.f;

    int i = b;
    for (; i + 1 < e; i += 2) {
        int s0 = csr[i], s1 = csr[i + 1];
        const float* p0 = in + (long long)s0 * sin;
        const float* p1 = in + (long long)s1 * sin;
        float v0[NV], v1[NV];
#pragma unroll
        for (int j = 0; j < NV; j++) v0[j] = p0[j * 64 + lane];
#pragma unroll
        for (int j = 0; j < NV; j++) v1[j] = p1[j * 64 + lane];
#pragma unroll
        for (int j = 0; j < NV; j++) acc[j] += v0[j] + v1[j];
    }
    if (i < e) {
        const float* p0 = in + (long long)csr[i] * sin;
#pragma unroll
        for (int j = 0; j < NV; j++) acc[j] += p0[j * 64 + lane];
    }
#pragma unroll
    for (int j = 0; j < NV; j++) out[(long long)node * sout + j * 64 + lane] = acc[j];
}

// ---------------- dense side (unchanged from R1) ----------------

template <int O, int TM>
__global__ __launch_bounds__(256) void sage_gemm_k(
    const float* __restrict__ A1, int s1, int K1, const float* __restrict__ W1,
    const float* __restrict__ A2, int s2, int K2, const float* __restrict__ W2,
    const float* __restrict__ bias, const float* __restrict__ inv,
    float* __restrict__ out, int so, int ocol)
{
    constexpr int OG = O / 4;
    constexpr int MG = 256 / OG;
    static_assert(MG * 4 == TM, "tile mismatch");
    constexpr int LDA = 68;
    __shared__ float ldsA[TM * LDA];
    __shared__ float ldsW[64 * O];

    const int tid = threadIdx.x;
    const int og = tid % OG;
    const int mg = tid / OG;
    const int node0 = blockIdx.x * TM;

    float acc[4][4];
#pragma unroll
    for (int a = 0; a < 4; a++)
#pragma unroll
        for (int b = 0; b < 4; b++) acc[a][b] = 0.f;

#pragma unroll 1
    for (int phase = 0; phase < 2; ++phase) {
        const float* A = phase ? A2 : A1;
        const float* W = phase ? W2 : W1;
        const int K = phase ? K2 : K1;
        const int sA = phase ? s2 : s1;

        if (phase == 1 && K1 > 0) {
#pragma unroll
            for (int mi = 0; mi < 4; mi++) {
                int node = node0 + 4 * mg + mi;
                float iv = (node < N_NODES) ? inv[node] : 0.f;
#pragma unroll
                for (int oi = 0; oi < 4; oi++) acc[mi][oi] *= iv;
            }
        }

#pragma unroll 1
        for (int k0 = 0; k0 < K; k0 += 64) {
            __syncthreads();
#pragma unroll
            for (int i = tid; i < TM * 16; i += 256) {
                int m = i / 16, kc = i % 16;
                int node = node0 + m;
                float4 v = {0.f, 0.f, 0.f, 0.f};
                if (node < N_NODES)
                    v = *(const float4*)&A[(long long)node * sA + k0 + 4 * kc];
                *(float4*)&ldsA[m * LDA + 4 * kc] = v;
            }
#pragma unroll
            for (int i = tid; i < 16 * O; i += 256) {
                int kr = i / OG, oc = (i % OG) * 4;
                *(float4*)&ldsW[kr * O + oc] = *(const float4*)&W[(long long)(k0 + kr) * O + oc];
            }
            __syncthreads();

#pragma unroll 4
            for (int kq = 0; kq < 16; kq++) {
                float4 a0 = *(const float4*)&ldsA[(4 * mg + 0) * LDA + 4 * kq];
                float4 a1 = *(const float4*)&ldsA[(4 * mg + 1) * LDA + 4 * kq];
                float4 a2 = *(const float4*)&ldsA[(4 * mg + 2) * LDA + 4 * kq];
                float4 a3 = *(const float4*)&ldsA[(4 * mg + 3) * LDA + 4 * kq];
                float4 w0 = *(const float4*)&ldsW[(4 * kq + 0) * O + 4 * og];
                float4 w1 = *(const float4*)&ldsW[(4 * kq + 1) * O + 4 * og];
                float4 w2 = *(const float4*)&ldsW[(4 * kq + 2) * O + 4 * og];
                float4 w3 = *(const float4*)&ldsW[(4 * kq + 3) * O + 4 * og];

                float aa[4][4] = {{a0.x, a0.y, a0.z, a0.w},
                                  {a1.x, a1.y, a1.z, a1.w},
                                  {a2.x, a2.y, a2.z, a2.w},
                                  {a3.x, a3.y, a3.z, a3.w}};
                float ww[4][4] = {{w0.x, w0.y, w0.z, w0.w},
                                  {w1.x, w1.y, w1.z, w1.w},
                                  {w2.x, w2.y, w2.z, w2.w},
                                  {w3.x, w3.y, w3.z, w3.w}};
#pragma unroll
                for (int mi = 0; mi < 4; mi++)
#pragma unroll
                    for (int oi = 0; oi < 4; oi++)
#pragma unroll
                        for (int kj = 0; kj < 4; kj++)
                            acc[mi][oi] += aa[mi][kj] * ww[kj][oi];
            }
        }
    }

#pragma unroll
    for (int mi = 0; mi < 4; mi++) {
        int node = node0 + 4 * mg + mi;
        if (node >= N_NODES) continue;
        float4 r;
        r.x = fmaxf(acc[mi][0] + bias[4 * og + 0], 0.f);
        r.y = fmaxf(acc[mi][1] + bias[4 * og + 1], 0.f);
        r.z = fmaxf(acc[mi][2] + bias[4 * og + 2], 0.f);
        r.w = fmaxf(acc[mi][3] + bias[4 * og + 3], 0.f);
        *(float4*)&out[(long long)node * so + ocol + 4 * og] = r;
    }
}

// ---------------- launch ----------------

extern "C" void kernel_launch(void* const* d_in, const int* in_sizes, int n_in,
                              void* d_out, int out_size, void* d_ws, size_t ws_size,
                              hipStream_t stream) {
    const float* x   = (const float*)d_in[0];
    const int*   ei  = (const int*)d_in[1];
    const float* Wp  = (const float*)d_in[2];
    const float* bp  = (const float*)d_in[3];
    const float* Wl1 = (const float*)d_in[4];
    const float* bl1 = (const float*)d_in[5];
    const float* Wr1 = (const float*)d_in[6];
    const float* Wl2 = (const float*)d_in[7];
    const float* bl2 = (const float*)d_in[8];
    const float* Wr2 = (const float*)d_in[9];
    const float* Wl3 = (const float*)d_in[10];
    const float* bl3 = (const float*)d_in[11];
    const float* Wr3 = (const float*)d_in[12];

    const int E = in_sizes[1] / 2;
    const int N = N_NODES;
    const int* src = ei;
    const int* dst = ei + E;
    const int NB = (N + 255) / 256;  // 196 scan blocks

    // workspace layout:
    // floats: feats [N,256] | agg [N,256] | aggx [N,64] | inv [N]
    // ints:   cnt[N] | incl[N] | row_ptr[N+1] | fillc[N] | bsum[256] | csr[E]
    float* feats = (float*)d_ws;
    float* agg   = feats + (size_t)N * 256;
    float* aggx  = agg   + (size_t)N * 256;
    float* inv   = aggx  + (size_t)N * 64;
    int* cnt     = (int*)(inv + N);
    int* incl    = cnt + N;
    int* row_ptr = incl + N;
    int* fillc   = row_ptr + (N + 1);
    int* bsum    = fillc + N;
    int* csr     = bsum + 256;

    hipMemsetAsync(cnt,   0, (size_t)N * sizeof(int), stream);
    hipMemsetAsync(fillc, 0, (size_t)N * sizeof(int), stream);

    // ---- CSR build ----
    count_edges_k<<<(E + 255) / 256, 256, 0, stream>>>(dst, E, cnt);
    make_inv_k<<<NB, 256, 0, stream>>>(cnt, inv, N);
    scan1_k<<<NB, 256, 0, stream>>>(cnt, N, incl, bsum);
    scan2_k<<<1, 256, 0, stream>>>(bsum, NB);
    scan3_k<<<NB, 256, 0, stream>>>(incl, cnt, bsum, N, E, row_ptr);
    fill_csr_k<<<(E + 255) / 256, 256, 0, stream>>>(src, dst, E, row_ptr, fillc, csr);

    // ---- x_p = relu(x @ Wp + bp) -> feats[:,0:64] ----
    sage_gemm_k<64, 64><<<(N + 63) / 64, 256, 0, stream>>>(
        nullptr, 0, 0, nullptr, x, 64, 64, Wp, bp, inv, feats, 256, 0);

    // ---- aggx = gather-sum(x) ----
    gather_k<1><<<(N + 3) / 4, 256, 0, stream>>>(row_ptr, csr, x, 64, aggx, 64);

    // ---- h1 -> feats[:,64:128] ----
    sage_gemm_k<64, 64><<<(N + 63) / 64, 256, 0, stream>>>(
        aggx, 64, 64, Wl1, x, 64, 64, Wr1, bl1, inv, feats, 256, 64);

    // ---- agg[:,0:128] = gather-sum(feats[:,0:128]) (reused by layers 2 and 3) ----
    gather_k<2><<<(N + 3) / 4, 256, 0, stream>>>(row_ptr, csr, feats, 256, agg, 256);

    // ---- h2 -> feats[:,128:256] ----
    sage_gemm_k<128, 32><<<(N + 31) / 32, 256, 0, stream>>>(
        agg, 256, 128, Wl2, feats, 256, 128, Wr2, bl2, inv, feats, 256, 128);

    // ---- agg[:,128:256] = gather-sum(feats[:,128:256]) ----
    gather_k<2><<<(N + 3) / 4, 256, 0, stream>>>(row_ptr, csr, feats + 128, 256, agg + 128, 256);

    // ---- h3 -> d_out ----
    sage_gemm_k<128, 32><<<(N + 31) / 32, 256, 0, stream>>>(
        agg, 256, 256, Wl3, feats, 256, 256, Wr3, bl3, inv, (float*)d_out, 128, 0);
}

// Round 3
// 409.617 us; speedup vs baseline: 9.0618x; 1.3382x over previous
//
#include <hip/hip_runtime.h>

#define N_NODES 50000

typedef unsigned int uint;
typedef unsigned short ushort;
typedef float floatx4 __attribute__((ext_vector_type(4)));
typedef short short8 __attribute__((ext_vector_type(8)));

__device__ inline ushort f2bf(float f) {
    uint u = __float_as_uint(f);
    return (ushort)((u + 0x7fffu + ((u >> 16) & 1u)) >> 16);
}
__device__ inline float bf2f(ushort h) { return __uint_as_float((uint)h << 16); }

// ---------------- CSR build ----------------

__global__ void count_edges_k(const int* __restrict__ dst, int E, int* __restrict__ cnt) {
    int t = blockIdx.x * 256 + threadIdx.x;
    if (t < E) atomicAdd(&cnt[dst[t]], 1);
}

__global__ void make_inv_k(const int* __restrict__ cnt, float* __restrict__ inv, int n) {
    int t = blockIdx.x * 256 + threadIdx.x;
    if (t < n) inv[t] = 1.0f / fmaxf((float)cnt[t], 1.0f);
}

__global__ void scan1_k(const int* __restrict__ cnt, int n,
                        int* __restrict__ incl, int* __restrict__ bsum) {
    __shared__ int s[256];
    int t = threadIdx.x, i = blockIdx.x * 256 + t;
    s[t] = (i < n) ? cnt[i] : 0;
    __syncthreads();
#pragma unroll
    for (int off = 1; off < 256; off <<= 1) {
        int u = (t >= off) ? s[t - off] : 0;
        __syncthreads();
        s[t] += u;
        __syncthreads();
    }
    if (i < n) incl[i] = s[t];
    if (t == 255) bsum[blockIdx.x] = s[255];
}

__global__ void scan2_k(int* __restrict__ bsum, int nb) {
    __shared__ int s[256];
    int t = threadIdx.x;
    s[t] = (t < nb) ? bsum[t] : 0;
    __syncthreads();
#pragma unroll
    for (int off = 1; off < 256; off <<= 1) {
        int u = (t >= off) ? s[t - off] : 0;
        __syncthreads();
        s[t] += u;
        __syncthreads();
    }
    int ex = (t == 0) ? 0 : s[t - 1];
    if (t < nb) bsum[t] = ex;
}

__global__ void scan3_k(const int* __restrict__ incl, const int* __restrict__ cnt,
                        const int* __restrict__ boff, int n, int E, int* __restrict__ row_ptr) {
    int i = blockIdx.x * 256 + threadIdx.x;
    if (i < n) row_ptr[i] = incl[i] - cnt[i] + boff[blockIdx.x];
    if (i == 0) row_ptr[n] = E;
}

__global__ void fill_csr_k(const int* __restrict__ src, const int* __restrict__ dst, int E,
                           const int* __restrict__ row_ptr, int* __restrict__ fillc,
                           int* __restrict__ csr) {
    int t = blockIdx.x * 256 + threadIdx.x;
    if (t < E) {
        int d = dst[t];
        int p = row_ptr[d] + atomicAdd(&fillc[d], 1);
        csr[p] = src[t];
    }
}

// ---------------- conversions ----------------

__global__ void f2bf4_k(const float* __restrict__ in, ushort* __restrict__ out, int n4) {
    int t = blockIdx.x * 256 + threadIdx.x;
    if (t >= n4) return;
    float4 v = ((const float4*)in)[t];
    ushort4 o;
    o.x = f2bf(v.x); o.y = f2bf(v.y); o.z = f2bf(v.z); o.w = f2bf(v.w);
    ((ushort4*)out)[t] = o;
}

// swizzle a [K,O] fp32 weight into MFMA B-fragment order (bf16):
// Wz[((c*(O/16)+nb)*64 + lane)*8 + j] = W[c*32 + (lane>>4)*8 + j][nb*16 + (lane&15)]
__global__ void swz_k(const float* __restrict__ W, ushort* __restrict__ Wz, int K, int O) {
    int t = blockIdx.x * 256 + threadIdx.x;
    int total = (K / 32) * (O / 16) * 64;
    if (t >= total) return;
    int lane = t & 63, cb = t >> 6;
    int NBm = O / 16;
    int c = cb / NBm, nb = cb % NBm;
    int quad = lane >> 4, l16 = lane & 15;
#pragma unroll
    for (int j = 0; j < 8; j++) {
        float v = W[(size_t)(c * 32 + quad * 8 + j) * O + nb * 16 + l16];
        Wz[(size_t)t * 8 + j] = f2bf(v);
    }
}

// ---------------- gather (mean, bf16 in/out, fp32 accumulate) ----------------

// 64 cols: lane = col
__global__ __launch_bounds__(256) void gather64_k(const int* __restrict__ row_ptr,
                                                  const int* __restrict__ csr,
                                                  const float* __restrict__ inv,
                                                  const ushort* __restrict__ in, int sin,
                                                  ushort* __restrict__ out, int sout) {
    int node = blockIdx.x * 4 + (threadIdx.x >> 6);
    if (node >= N_NODES) return;
    int lane = threadIdx.x & 63;
    int b = row_ptr[node], e = row_ptr[node + 1];
    float acc = 0.f;
    int i = b;
    for (; i + 1 < e; i += 2) {
        int s0 = csr[i], s1 = csr[i + 1];
        acc += bf2f(in[(size_t)s0 * sin + lane]) + bf2f(in[(size_t)s1 * sin + lane]);
    }
    if (i < e) acc += bf2f(in[(size_t)csr[i] * sin + lane]);
    out[(size_t)node * sout + lane] = f2bf(acc * inv[node]);
}

// 128 cols: lane owns cols {2*lane, 2*lane+1} via uint
__global__ __launch_bounds__(256) void gather128_k(const int* __restrict__ row_ptr,
                                                   const int* __restrict__ csr,
                                                   const float* __restrict__ inv,
                                                   const ushort* __restrict__ in, int sin,
                                                   ushort* __restrict__ out, int sout) {
    int node = blockIdx.x * 4 + (threadIdx.x >> 6);
    if (node >= N_NODES) return;
    int lane = threadIdx.x & 63;
    int b = row_ptr[node], e = row_ptr[node + 1];
    float a0 = 0.f, a1 = 0.f;
    int i = b;
    for (; i + 1 < e; i += 2) {
        int s0 = csr[i], s1 = csr[i + 1];
        uint u0 = *(const uint*)&in[(size_t)s0 * sin + 2 * lane];
        uint u1 = *(const uint*)&in[(size_t)s1 * sin + 2 * lane];
        a0 += __uint_as_float(u0 << 16) + __uint_as_float(u1 << 16);
        a1 += __uint_as_float(u0 & 0xffff0000u) + __uint_as_float(u1 & 0xffff0000u);
    }
    if (i < e) {
        uint u0 = *(const uint*)&in[(size_t)csr[i] * sin + 2 * lane];
        a0 += __uint_as_float(u0 << 16);
        a1 += __uint_as_float(u0 & 0xffff0000u);
    }
    float iv = inv[node];
    uint r = (uint)f2bf(a0 * iv) | ((uint)f2bf(a1 * iv) << 16);
    *(uint*)&out[(size_t)node * sout + 2 * lane] = r;
}

// ---------------- MFMA GEMM ----------------
// out[i, ocol+n] = relu( (A1[i,:K1] @ W1)[n] + (A2[i,:K2] @ W2)[n] + bias[n] )
// A1/A2 bf16 row-major; W1/W2 pre-swizzled B-fragment order (swz_k).
// block = 256 thr = 4 waves; tile 64 rows x O cols; wave w owns rows 16w..16w+15.

template <int O, bool OUT_BF16>
__global__ __launch_bounds__(256) void mfma_gemm_k(
    const ushort* __restrict__ A1, int s1, int K1, const ushort* __restrict__ Wz1,
    const ushort* __restrict__ A2, int s2, int K2, const ushort* __restrict__ Wz2,
    const float* __restrict__ bias, void* __restrict__ outp, int so, int ocol)
{
    constexpr int NB = O / 16;
    constexpr int LDA = 40;  // bf16; 80 B row stride (16B-aligned, 2-way banks)
    __shared__ ushort ldsA[64 * LDA];

    const int tid = threadIdx.x;
    const int wave = tid >> 6, lane = tid & 63;
    const int quad = lane >> 4, l16 = lane & 15;
    const int node0 = blockIdx.x * 64;

    floatx4 acc[NB];
#pragma unroll
    for (int nb = 0; nb < NB; nb++) acc[nb] = (floatx4){0.f, 0.f, 0.f, 0.f};

#pragma unroll 1
    for (int phase = 0; phase < 2; ++phase) {
        const ushort* A = phase ? A2 : A1;
        const ushort* Wz = phase ? Wz2 : Wz1;
        const int K = phase ? K2 : K1;
        const int sA = phase ? s2 : s1;

#pragma unroll 1
        for (int k0 = 0; k0 < K; k0 += 32) {
            __syncthreads();
            {   // stage A: 64 rows x 32 bf16; thread t -> row t/4, 8-bf16 segment t%4
                int row = tid >> 2, seg = tid & 3;
                int node = node0 + row;
                uint4 v = {0u, 0u, 0u, 0u};
                if (node < N_NODES)
                    v = *(const uint4*)&A[(size_t)node * sA + k0 + seg * 8];
                *(uint4*)&ldsA[row * LDA + seg * 8] = v;
            }
            __syncthreads();

            short8 a = *(const short8*)&ldsA[(wave * 16 + l16) * LDA + quad * 8];
            const short8* bz = (const short8*)Wz + (size_t)(k0 >> 5) * NB * 64;
#pragma unroll
            for (int nb = 0; nb < NB; nb++) {
                short8 b = bz[nb * 64 + lane];
                acc[nb] = __builtin_amdgcn_mfma_f32_16x16x32_bf16(a, b, acc[nb], 0, 0, 0);
            }
        }
    }

    // epilogue: bias + relu; D layout: col = lane&15, row = quad*4 + r
#pragma unroll
    for (int nb = 0; nb < NB; nb++) {
        int ncol = nb * 16 + l16;
        float bv = bias[ncol];
#pragma unroll
        for (int r = 0; r < 4; r++) {
            int node = node0 + wave * 16 + quad * 4 + r;
            if (node >= N_NODES) continue;
            float v = fmaxf(acc[nb][r] + bv, 0.f);
            if (OUT_BF16)
                ((ushort*)outp)[(size_t)node * so + ocol + ncol] = f2bf(v);
            else
                ((float*)outp)[(size_t)node * so + ocol + ncol] = v;
        }
    }
}

// ---------------- launch ----------------

extern "C" void kernel_launch(void* const* d_in, const int* in_sizes, int n_in,
                              void* d_out, int out_size, void* d_ws, size_t ws_size,
                              hipStream_t stream) {
    const float* x   = (const float*)d_in[0];
    const int*   ei  = (const int*)d_in[1];
    const float* Wp  = (const float*)d_in[2];
    const float* bp  = (const float*)d_in[3];
    const float* Wl1 = (const float*)d_in[4];
    const float* bl1 = (const float*)d_in[5];
    const float* Wr1 = (const float*)d_in[6];
    const float* Wl2 = (const float*)d_in[7];
    const float* bl2 = (const float*)d_in[8];
    const float* Wr2 = (const float*)d_in[9];
    const float* Wl3 = (const float*)d_in[10];
    const float* bl3 = (const float*)d_in[11];
    const float* Wr3 = (const float*)d_in[12];

    const int E = in_sizes[1] / 2;
    const int N = N_NODES;
    const int* src = ei;
    const int* dst = ei + E;
    const int NBLK = (N + 255) / 256;

    // ---- workspace carve-up (16B-aligned regions) ----
    char* p = (char*)d_ws;
    ushort* xb    = (ushort*)p;              p += (size_t)N * 64 * 2;
    ushort* feats = (ushort*)p;              p += (size_t)N * 256 * 2;
    ushort* aggx  = (ushort*)p;              p += (size_t)N * 64 * 2;
    ushort* aggf  = (ushort*)p;              p += (size_t)N * 256 * 2;
    float*  inv   = (float*)p;               p += (size_t)N * 4;
    int* cnt      = (int*)p;                 p += (size_t)N * 4;
    int* incl     = (int*)p;                 p += (size_t)N * 4;
    int* row_ptr  = (int*)p;                 p += (size_t)(N + 4) * 4;
    int* fillc    = (int*)p;                 p += (size_t)N * 4;
    int* bsum     = (int*)p;                 p += 256 * 4;
    int* csr      = (int*)p;                 p += (size_t)E * 4;
    ushort* zp    = (ushort*)p;              p += 64 * 64 * 2;
    ushort* zl1   = (ushort*)p;              p += 64 * 64 * 2;
    ushort* zr1   = (ushort*)p;              p += 64 * 64 * 2;
    ushort* zl2   = (ushort*)p;              p += 128 * 128 * 2;
    ushort* zr2   = (ushort*)p;              p += 128 * 128 * 2;
    ushort* zl3   = (ushort*)p;              p += 256 * 128 * 2;
    ushort* zr3   = (ushort*)p;              p += 256 * 128 * 2;

    hipMemsetAsync(cnt,   0, (size_t)N * sizeof(int), stream);
    hipMemsetAsync(fillc, 0, (size_t)N * sizeof(int), stream);

    // ---- CSR build ----
    count_edges_k<<<(E + 255) / 256, 256, 0, stream>>>(dst, E, cnt);
    make_inv_k<<<NBLK, 256, 0, stream>>>(cnt, inv, N);
    scan1_k<<<NBLK, 256, 0, stream>>>(cnt, N, incl, bsum);
    scan2_k<<<1, 256, 0, stream>>>(bsum, NBLK);
    scan3_k<<<NBLK, 256, 0, stream>>>(incl, cnt, bsum, N, E, row_ptr);
    fill_csr_k<<<(E + 255) / 256, 256, 0, stream>>>(src, dst, E, row_ptr, fillc, csr);

    // ---- weight swizzle + x conversion ----
    f2bf4_k<<<(N * 64 / 4 + 255) / 256, 256, 0, stream>>>(x, xb, N * 64 / 4);
    swz_k<<<((64/32)*(64/16)*64 + 255) / 256, 256, 0, stream>>>(Wp,  zp,  64, 64);
    swz_k<<<((64/32)*(64/16)*64 + 255) / 256, 256, 0, stream>>>(Wl1, zl1, 64, 64);
    swz_k<<<((64/32)*(64/16)*64 + 255) / 256, 256, 0, stream>>>(Wr1, zr1, 64, 64);
    swz_k<<<((128/32)*(128/16)*64 + 255) / 256, 256, 0, stream>>>(Wl2, zl2, 128, 128);
    swz_k<<<((128/32)*(128/16)*64 + 255) / 256, 256, 0, stream>>>(Wr2, zr2, 128, 128);
    swz_k<<<((256/32)*(128/16)*64 + 255) / 256, 256, 0, stream>>>(Wl3, zl3, 256, 128);
    swz_k<<<((256/32)*(128/16)*64 + 255) / 256, 256, 0, stream>>>(Wr3, zr3, 256, 128);

    const int GG = (N + 63) / 64;  // 782 gemm blocks

    // ---- x_p = relu(x @ Wp + bp) -> feats[:,0:64] ----
    mfma_gemm_k<64, true><<<GG, 256, 0, stream>>>(
        nullptr, 0, 0, nullptr, xb, 64, 64, zp, bp, feats, 256, 0);

    // ---- aggx = mean-gather(xb) ----
    gather64_k<<<(N + 3) / 4, 256, 0, stream>>>(row_ptr, csr, inv, xb, 64, aggx, 64);

    // ---- h1 -> feats[:,64:128] ----
    mfma_gemm_k<64, true><<<GG, 256, 0, stream>>>(
        aggx, 64, 64, zl1, xb, 64, 64, zr1, bl1, feats, 256, 64);

    // ---- aggf[:,0:128] = mean-gather(feats[:,0:128]) (layers 2 and 3) ----
    gather128_k<<<(N + 3) / 4, 256, 0, stream>>>(row_ptr, csr, inv, feats, 256, aggf, 256);

    // ---- h2 -> feats[:,128:256] ----
    mfma_gemm_k<128, true><<<GG, 256, 0, stream>>>(
        aggf, 256, 128, zl2, feats, 256, 128, zr2, bl2, feats, 256, 128);

    // ---- aggf[:,128:256] = mean-gather(h2) ----
    gather128_k<<<(N + 3) / 4, 256, 0, stream>>>(row_ptr, csr, inv, feats + 128, 256, aggf + 128, 256);

    // ---- h3 -> d_out (fp32) ----
    mfma_gemm_k<128, false><<<GG, 256, 0, stream>>>(
        aggf, 256, 256, zl3, feats, 256, 256, zr3, bl3, (float*)d_out, 128, 0);
}

// Round 4
// 319.450 us; speedup vs baseline: 11.6195x; 1.2823x over previous
//
#include <hip/hip_runtime.h>

#define N_NODES 50000
#define ELLW 64          // ELL width; P(deg>64) ~ 1e-17 for Poisson(16)
#define NCVT 3125        // N*64/4/256 blocks for the x->bf16 convert

typedef unsigned int uint;
typedef unsigned short ushort;
typedef float floatx4 __attribute__((ext_vector_type(4)));
typedef short short8 __attribute__((ext_vector_type(8)));

__device__ inline ushort f2bf(float f) {
    uint u = __float_as_uint(f);
    return (ushort)((u + 0x7fffu + ((u >> 16) & 1u)) >> 16);
}
__device__ inline float bflo(uint u) { return __uint_as_float(u << 16); }
__device__ inline float bfhi(uint u) { return __uint_as_float(u & 0xffff0000u); }

// ---------------- ELL build (single pass, ILP-4) ----------------

__global__ __launch_bounds__(256) void fill_ell_k(const int* __restrict__ src,
                                                  const int* __restrict__ dst, int E,
                                                  int* __restrict__ fillc,
                                                  ushort* __restrict__ ell) {
    int t0 = blockIdx.x * 1024 + threadIdx.x;
#pragma unroll
    for (int j = 0; j < 4; j++) {
        int t = t0 + j * 256;
        if (t < E) {
            int d = dst[t], s = src[t];
            int p = atomicAdd(&fillc[d], 1);
            if (p < ELLW) ell[(size_t)d * ELLW + p] = (ushort)s;
        }
    }
}

// ---------------- fused convert + weight swizzle ----------------
// swizzle [K,O] fp32 weight into MFMA B-frag order:
// Wz[((c*(O/16)+nb)*64 + lane)*8 + j] = W[c*32 + (lane>>4)*8 + j][nb*16 + (lane&15)]

__device__ inline void swz_body(const float* __restrict__ W, ushort* __restrict__ Wz,
                                int O, int t) {
    int lane = t & 63, cb = t >> 6;
    int NBm = O / 16;
    int c = cb / NBm, nb = cb % NBm;
    int quad = lane >> 4, l16 = lane & 15;
#pragma unroll
    for (int j = 0; j < 8; j++) {
        float v = W[(size_t)(c * 32 + quad * 8 + j) * O + nb * 16 + l16];
        Wz[(size_t)t * 8 + j] = f2bf(v);
    }
}

__global__ __launch_bounds__(256) void cvt_swz_k(
    const float* __restrict__ x, ushort* __restrict__ xb,
    const float* __restrict__ Wp, ushort* __restrict__ zp,
    const float* __restrict__ Wl1, ushort* __restrict__ zl1,
    const float* __restrict__ Wr1, ushort* __restrict__ zr1,
    const float* __restrict__ Wl2, ushort* __restrict__ zl2,
    const float* __restrict__ Wr2, ushort* __restrict__ zr2,
    const float* __restrict__ Wl3, ushort* __restrict__ zl3,
    const float* __restrict__ Wr3, ushort* __restrict__ zr3) {
    int b = blockIdx.x, tid = threadIdx.x;
    if (b < NCVT) {
        int t = b * 256 + tid;
        float4 v = ((const float4*)x)[t];
        ushort4 o;
        o.x = f2bf(v.x); o.y = f2bf(v.y); o.z = f2bf(v.z); o.w = f2bf(v.w);
        ((ushort4*)xb)[t] = o;
        return;
    }
    b -= NCVT;
    // block counts per segment: 2,2,2,8,8,16,16 (total 54)
    if      (b < 2)  swz_body(Wp,  zp,  64,  (b - 0) * 256 + tid);
    else if (b < 4)  swz_body(Wl1, zl1, 64,  (b - 2) * 256 + tid);
    else if (b < 6)  swz_body(Wr1, zr1, 64,  (b - 4) * 256 + tid);
    else if (b < 14) swz_body(Wl2, zl2, 128, (b - 6) * 256 + tid);
    else if (b < 22) swz_body(Wr2, zr2, 128, (b - 14) * 256 + tid);
    else if (b < 38) swz_body(Wl3, zl3, 128, (b - 22) * 256 + tid);
    else             swz_body(Wr3, zr3, 128, (b - 38) * 256 + tid);
}

// ---------------- gathers (mean, bf16, half-wave edge split) ----------------
// wave per node; lanes 0-31 take even edge slots, 32-63 odd; combine via shfl_xor(32).

__global__ __launch_bounds__(256) void gather64_k(const int* __restrict__ fillc,
                                                  const ushort* __restrict__ ell,
                                                  const ushort* __restrict__ in, int sin,
                                                  ushort* __restrict__ out, int sout) {
    int node = blockIdx.x * 4 + (threadIdx.x >> 6);
    if (node >= N_NODES) return;
    int lane = threadIdx.x & 63;
    int half = lane >> 5, c = lane & 31;      // cols {2c, 2c+1}
    int n = fillc[node]; int nc = (n > ELLW) ? ELLW : n;
    const ushort* base = ell + (size_t)node * ELLW;
    float a0 = 0.f, a1 = 0.f;
    int i = half;
    for (; i + 2 < nc; i += 4) {
        int s0 = base[i], s1 = base[i + 2];
        uint u0 = *(const uint*)&in[(size_t)s0 * sin + 2 * c];
        uint u1 = *(const uint*)&in[(size_t)s1 * sin + 2 * c];
        a0 += bflo(u0) + bflo(u1);
        a1 += bfhi(u0) + bfhi(u1);
    }
    if (i < nc) {
        uint u0 = *(const uint*)&in[(size_t)base[i] * sin + 2 * c];
        a0 += bflo(u0);
        a1 += bfhi(u0);
    }
    a0 += __shfl_xor(a0, 32);
    a1 += __shfl_xor(a1, 32);
    if (half == 0) {
        float iv = 1.0f / fmaxf((float)n, 1.0f);
        uint r = (uint)f2bf(a0 * iv) | ((uint)f2bf(a1 * iv) << 16);
        *(uint*)&out[(size_t)node * sout + 2 * c] = r;
    }
}

__global__ __launch_bounds__(256) void gather128_k(const int* __restrict__ fillc,
                                                   const ushort* __restrict__ ell,
                                                   const ushort* __restrict__ in, int sin,
                                                   ushort* __restrict__ out, int sout) {
    int node = blockIdx.x * 4 + (threadIdx.x >> 6);
    if (node >= N_NODES) return;
    int lane = threadIdx.x & 63;
    int half = lane >> 5, c = lane & 31;      // cols {4c..4c+3}
    int n = fillc[node]; int nc = (n > ELLW) ? ELLW : n;
    const ushort* base = ell + (size_t)node * ELLW;
    float a0 = 0.f, a1 = 0.f, a2 = 0.f, a3 = 0.f;
    int i = half;
    for (; i + 2 < nc; i += 4) {
        int s0 = base[i], s1 = base[i + 2];
        uint2 u0 = *(const uint2*)&in[(size_t)s0 * sin + 4 * c];
        uint2 u1 = *(const uint2*)&in[(size_t)s1 * sin + 4 * c];
        a0 += bflo(u0.x) + bflo(u1.x);
        a1 += bfhi(u0.x) + bfhi(u1.x);
        a2 += bflo(u0.y) + bflo(u1.y);
        a3 += bfhi(u0.y) + bfhi(u1.y);
    }
    if (i < nc) {
        uint2 u0 = *(const uint2*)&in[(size_t)base[i] * sin + 4 * c];
        a0 += bflo(u0.x); a1 += bfhi(u0.x);
        a2 += bflo(u0.y); a3 += bfhi(u0.y);
    }
    a0 += __shfl_xor(a0, 32);
    a1 += __shfl_xor(a1, 32);
    a2 += __shfl_xor(a2, 32);
    a3 += __shfl_xor(a3, 32);
    if (half == 0) {
        float iv = 1.0f / fmaxf((float)n, 1.0f);
        uint2 r;
        r.x = (uint)f2bf(a0 * iv) | ((uint)f2bf(a1 * iv) << 16);
        r.y = (uint)f2bf(a2 * iv) | ((uint)f2bf(a3 * iv) << 16);
        *(uint2*)&out[(size_t)node * sout + 4 * c] = r;
    }
}

// ---------------- MFMA GEMM (unchanged from R3) ----------------
// out[i, ocol+n] = relu( (A1[i,:K1] @ W1)[n] + (A2[i,:K2] @ W2)[n] + bias[n] )

template <int O, bool OUT_BF16>
__global__ __launch_bounds__(256) void mfma_gemm_k(
    const ushort* __restrict__ A1, int s1, int K1, const ushort* __restrict__ Wz1,
    const ushort* __restrict__ A2, int s2, int K2, const ushort* __restrict__ Wz2,
    const float* __restrict__ bias, void* __restrict__ outp, int so, int ocol)
{
    constexpr int NB = O / 16;
    constexpr int LDA = 40;  // bf16; 80 B row stride (16B-aligned, banks spread)
    __shared__ ushort ldsA[64 * LDA];

    const int tid = threadIdx.x;
    const int wave = tid >> 6, lane = tid & 63;
    const int quad = lane >> 4, l16 = lane & 15;
    const int node0 = blockIdx.x * 64;

    floatx4 acc[NB];
#pragma unroll
    for (int nb = 0; nb < NB; nb++) acc[nb] = (floatx4){0.f, 0.f, 0.f, 0.f};

#pragma unroll 1
    for (int phase = 0; phase < 2; ++phase) {
        const ushort* A = phase ? A2 : A1;
        const ushort* Wz = phase ? Wz2 : Wz1;
        const int K = phase ? K2 : K1;
        const int sA = phase ? s2 : s1;

#pragma unroll 1
        for (int k0 = 0; k0 < K; k0 += 32) {
            __syncthreads();
            {   // stage A: 64 rows x 32 bf16
                int row = tid >> 2, seg = tid & 3;
                int node = node0 + row;
                uint4 v = {0u, 0u, 0u, 0u};
                if (node < N_NODES)
                    v = *(const uint4*)&A[(size_t)node * sA + k0 + seg * 8];
                *(uint4*)&ldsA[row * LDA + seg * 8] = v;
            }
            __syncthreads();

            short8 a = *(const short8*)&ldsA[(wave * 16 + l16) * LDA + quad * 8];
            const short8* bz = (const short8*)Wz + (size_t)(k0 >> 5) * NB * 64;
#pragma unroll
            for (int nb = 0; nb < NB; nb++) {
                short8 b = bz[nb * 64 + lane];
                acc[nb] = __builtin_amdgcn_mfma_f32_16x16x32_bf16(a, b, acc[nb], 0, 0, 0);
            }
        }
    }

#pragma unroll
    for (int nb = 0; nb < NB; nb++) {
        int ncol = nb * 16 + l16;
        float bv = bias[ncol];
#pragma unroll
        for (int r = 0; r < 4; r++) {
            int node = node0 + wave * 16 + quad * 4 + r;
            if (node >= N_NODES) continue;
            float v = fmaxf(acc[nb][r] + bv, 0.f);
            if (OUT_BF16)
                ((ushort*)outp)[(size_t)node * so + ocol + ncol] = f2bf(v);
            else
                ((float*)outp)[(size_t)node * so + ocol + ncol] = v;
        }
    }
}

// ---------------- launch ----------------

extern "C" void kernel_launch(void* const* d_in, const int* in_sizes, int n_in,
                              void* d_out, int out_size, void* d_ws, size_t ws_size,
                              hipStream_t stream) {
    const float* x   = (const float*)d_in[0];
    const int*   ei  = (const int*)d_in[1];
    const float* Wp  = (const float*)d_in[2];
    const float* bp  = (const float*)d_in[3];
    const float* Wl1 = (const float*)d_in[4];
    const float* bl1 = (const float*)d_in[5];
    const float* Wr1 = (const float*)d_in[6];
    const float* Wl2 = (const float*)d_in[7];
    const float* bl2 = (const float*)d_in[8];
    const float* Wr2 = (const float*)d_in[9];
    const float* Wl3 = (const float*)d_in[10];
    const float* bl3 = (const float*)d_in[11];
    const float* Wr3 = (const float*)d_in[12];

    const int E = in_sizes[1] / 2;
    const int N = N_NODES;
    const int* src = ei;
    const int* dst = ei + E;

    // ---- workspace carve-up (all offsets 16B-aligned) ----
    char* p = (char*)d_ws;
    ushort* xb    = (ushort*)p;  p += (size_t)N * 64 * 2;
    ushort* feats = (ushort*)p;  p += (size_t)N * 256 * 2;
    ushort* aggx  = (ushort*)p;  p += (size_t)N * 64 * 2;
    ushort* aggf  = (ushort*)p;  p += (size_t)N * 256 * 2;
    int* fillc    = (int*)p;     p += (size_t)N * 4;
    ushort* ell   = (ushort*)p;  p += (size_t)N * ELLW * 2;
    ushort* zp    = (ushort*)p;  p += 64 * 64 * 2;
    ushort* zl1   = (ushort*)p;  p += 64 * 64 * 2;
    ushort* zr1   = (ushort*)p;  p += 64 * 64 * 2;
    ushort* zl2   = (ushort*)p;  p += 128 * 128 * 2;
    ushort* zr2   = (ushort*)p;  p += 128 * 128 * 2;
    ushort* zl3   = (ushort*)p;  p += 256 * 128 * 2;
    ushort* zr3   = (ushort*)p;  p += 256 * 128 * 2;

    hipMemsetAsync(fillc, 0, (size_t)N * sizeof(int), stream);

    // ---- ELL build (replaces count+scan+fill) ----
    fill_ell_k<<<(E + 1023) / 1024, 256, 0, stream>>>(src, dst, E, fillc, ell);

    // ---- fused x->bf16 + all weight swizzles ----
    cvt_swz_k<<<NCVT + 54, 256, 0, stream>>>(x, xb, Wp, zp, Wl1, zl1, Wr1, zr1,
                                             Wl2, zl2, Wr2, zr2, Wl3, zl3, Wr3, zr3);

    const int GG = (N + 63) / 64;

    // ---- x_p = relu(x @ Wp + bp) -> feats[:,0:64] ----
    mfma_gemm_k<64, true><<<GG, 256, 0, stream>>>(
        nullptr, 0, 0, nullptr, xb, 64, 64, zp, bp, feats, 256, 0);

    // ---- aggx = mean-gather(xb) ----
    gather64_k<<<(N + 3) / 4, 256, 0, stream>>>(fillc, ell, xb, 64, aggx, 64);

    // ---- h1 -> feats[:,64:128] ----
    mfma_gemm_k<64, true><<<GG, 256, 0, stream>>>(
        aggx, 64, 64, zl1, xb, 64, 64, zr1, bl1, feats, 256, 64);

    // ---- aggf[:,0:128] = mean-gather(feats[:,0:128]) (layers 2 and 3) ----
    gather128_k<<<(N + 3) / 4, 256, 0, stream>>>(fillc, ell, feats, 256, aggf, 256);

    // ---- h2 -> feats[:,128:256] ----
    mfma_gemm_k<128, true><<<GG, 256, 0, stream>>>(
        aggf, 256, 128, zl2, feats, 256, 128, zr2, bl2, feats, 256, 128);

    // ---- aggf[:,128:256] = mean-gather(h2) ----
    gather128_k<<<(N + 3) / 4, 256, 0, stream>>>(fillc, ell, feats + 128, 256, aggf + 128, 256);

    // ---- h3 -> d_out (fp32) ----
    mfma_gemm_k<128, false><<<GG, 256, 0, stream>>>(
        aggf, 256, 256, zl3, feats, 256, 256, zr3, bl3, (float*)d_out, 128, 0);
}

// Round 5
// 302.283 us; speedup vs baseline: 12.2794x; 1.0568x over previous
//
#include <hip/hip_runtime.h>

#define N_NODES 50000
#define ELLW 48          // ELL width; P(deg>48) ~ 1e-15 for Poisson(16)

typedef unsigned int uint;
typedef unsigned short ushort;
typedef float floatx4 __attribute__((ext_vector_type(4)));
typedef short short8 __attribute__((ext_vector_type(8)));

__device__ inline ushort f2bf(float f) {
    uint u = __float_as_uint(f);
    return (ushort)((u + 0x7fffu + ((u >> 16) & 1u)) >> 16);
}
__device__ inline float bflo(uint u) { return __uint_as_float(u << 16); }
__device__ inline float bfhi(uint u) { return __uint_as_float(u & 0xffff0000u); }

// ---------------- K1 mega-kernel bodies ----------------

// swizzle [K,O] fp32 weight into MFMA B-frag order:
// Wz[((c*(O/16)+nb)*64 + lane)*8 + j] = W[c*32 + (lane>>4)*8 + j][nb*16 + (lane&15)]
__device__ inline void swz_body(const float* __restrict__ W, ushort* __restrict__ Wz,
                                int O, int t) {
    int lane = t & 63, cb = t >> 6;
    int NBm = O / 16;
    int c = cb / NBm, nb = cb % NBm;
    int quad = lane >> 4, l16 = lane & 15;
#pragma unroll
    for (int j = 0; j < 8; j++) {
        float v = W[(size_t)(c * 32 + quad * 8 + j) * O + nb * 16 + l16];
        Wz[(size_t)t * 8 + j] = f2bf(v);
    }
}

// GEMM1: x_p = relu(x @ Wp + bp); reads fp32 x directly, swizzles Wp inline
// (so it has no dependency on the cvt/swz blocks running in the same dispatch).
__device__ void gemm1_body(int gb, const float* __restrict__ x,
                           const float* __restrict__ Wp, const float* __restrict__ bp,
                           ushort* __restrict__ feats, ushort* ldsA) {
    constexpr int LDA = 40;
    const int tid = threadIdx.x;
    const int wave = tid >> 6, lane = tid & 63;
    const int quad = lane >> 4, l16 = lane & 15;
    const int node0 = gb * 64;

    floatx4 acc[4];
#pragma unroll
    for (int nb = 0; nb < 4; nb++) acc[nb] = (floatx4){0.f, 0.f, 0.f, 0.f};

#pragma unroll
    for (int kk = 0; kk < 2; kk++) {
        const int k0 = kk * 32;
        __syncthreads();
        {   // stage A: 64 rows x 32 fp32 -> bf16 LDS
            int row = tid >> 2, seg = tid & 3;
            int node = node0 + row;
            float4 v0 = {0.f,0.f,0.f,0.f}, v1 = {0.f,0.f,0.f,0.f};
            if (node < N_NODES) {
                v0 = *(const float4*)&x[(size_t)node * 64 + k0 + seg * 8];
                v1 = *(const float4*)&x[(size_t)node * 64 + k0 + seg * 8 + 4];
            }
            ushort4 o0, o1;
            o0.x = f2bf(v0.x); o0.y = f2bf(v0.y); o0.z = f2bf(v0.z); o0.w = f2bf(v0.w);
            o1.x = f2bf(v1.x); o1.y = f2bf(v1.y); o1.z = f2bf(v1.z); o1.w = f2bf(v1.w);
            *(ushort4*)&ldsA[row * LDA + seg * 8] = o0;
            *(ushort4*)&ldsA[row * LDA + seg * 8 + 4] = o1;
        }
        __syncthreads();

        short8 a = *(const short8*)&ldsA[(wave * 16 + l16) * LDA + quad * 8];
#pragma unroll
        for (int nb = 0; nb < 4; nb++) {
            short8 bfrag;
#pragma unroll
            for (int j = 0; j < 8; j++)
                bfrag[j] = (short)f2bf(Wp[(size_t)(k0 + quad * 8 + j) * 64 + nb * 16 + l16]);
            acc[nb] = __builtin_amdgcn_mfma_f32_16x16x32_bf16(a, bfrag, acc[nb], 0, 0, 0);
        }
    }

#pragma unroll
    for (int nb = 0; nb < 4; nb++) {
        int ncol = nb * 16 + l16;
        float bv = bp[ncol];
#pragma unroll
        for (int r = 0; r < 4; r++) {
            int node = node0 + wave * 16 + quad * 4 + r;
            if (node >= N_NODES) continue;
            float v = fmaxf(acc[nb][r] + bv, 0.f);
            feats[(size_t)node * 256 + ncol] = f2bf(v);
        }
    }
}

// fused: [ELL fill | GEMM1 | x->bf16 convert | weight swizzles] — mutually independent
__global__ __launch_bounds__(256) void k1_mega(
    const int* __restrict__ src, const int* __restrict__ dst, int E,
    int* __restrict__ fillc, ushort* __restrict__ ell,
    const float* __restrict__ x, ushort* __restrict__ xb,
    const float* __restrict__ Wp, const float* __restrict__ bp, ushort* __restrict__ feats,
    const float* __restrict__ Wl1, ushort* __restrict__ zl1,
    const float* __restrict__ Wr1, ushort* __restrict__ zr1,
    const float* __restrict__ Wl2, ushort* __restrict__ zl2,
    const float* __restrict__ Wr2, ushort* __restrict__ zr2,
    const float* __restrict__ Wl3, ushort* __restrict__ zl3,
    const float* __restrict__ Wr3, ushort* __restrict__ zr3,
    int NF, int NG, int NC)
{
    __shared__ ushort ldsA[64 * 40];
    int b = blockIdx.x, tid = threadIdx.x;
    if (b < NF) {                       // ELL fill: 1 thread per edge (max TLP)
        int t = b * 256 + tid;
        if (t < E) {
            int d = dst[t], s = src[t];
            int p = atomicAdd(&fillc[d], 1);
            if (p < ELLW) ell[(size_t)d * ELLW + p] = (ushort)s;
        }
        return;
    }
    b -= NF;
    if (b < NG) { gemm1_body(b, x, Wp, bp, feats, ldsA); return; }
    b -= NG;
    if (b < NC) {                       // x -> bf16
        int t = b * 256 + tid;
        float4 v = ((const float4*)x)[t];
        ushort4 o;
        o.x = f2bf(v.x); o.y = f2bf(v.y); o.z = f2bf(v.z); o.w = f2bf(v.w);
        ((ushort4*)xb)[t] = o;
        return;
    }
    b -= NC;
    // weight swizzles: 2,2,8,8,16,16 blocks (52 total)
    if      (b < 2)  swz_body(Wl1, zl1, 64,  (b - 0) * 256 + tid);
    else if (b < 4)  swz_body(Wr1, zr1, 64,  (b - 2) * 256 + tid);
    else if (b < 12) swz_body(Wl2, zl2, 128, (b - 4) * 256 + tid);
    else if (b < 20) swz_body(Wr2, zr2, 128, (b - 12) * 256 + tid);
    else if (b < 36) swz_body(Wl3, zl3, 128, (b - 20) * 256 + tid);
    else             swz_body(Wr3, zr3, 128, (b - 36) * 256 + tid);
}

// ---------------- gathers (mean, bf16, half-wave edge split) ----------------

__global__ __launch_bounds__(256) void gather64_k(const int* __restrict__ fillc,
                                                  const ushort* __restrict__ ell,
                                                  const ushort* __restrict__ in, int sin,
                                                  ushort* __restrict__ out, int sout) {
    int node = blockIdx.x * 4 + (threadIdx.x >> 6);
    if (node >= N_NODES) return;
    int lane = threadIdx.x & 63;
    int half = lane >> 5, c = lane & 31;      // cols {2c, 2c+1}
    int n = fillc[node]; int nc = (n > ELLW) ? ELLW : n;
    const ushort* base = ell + (size_t)node * ELLW;
    float a0 = 0.f, a1 = 0.f;
    int i = half;
    for (; i + 2 < nc; i += 4) {
        int s0 = base[i], s1 = base[i + 2];
        uint u0 = *(const uint*)&in[(size_t)s0 * sin + 2 * c];
        uint u1 = *(const uint*)&in[(size_t)s1 * sin + 2 * c];
        a0 += bflo(u0) + bflo(u1);
        a1 += bfhi(u0) + bfhi(u1);
    }
    if (i < nc) {
        uint u0 = *(const uint*)&in[(size_t)base[i] * sin + 2 * c];
        a0 += bflo(u0);
        a1 += bfhi(u0);
    }
    a0 += __shfl_xor(a0, 32);
    a1 += __shfl_xor(a1, 32);
    if (half == 0) {
        float iv = 1.0f / fmaxf((float)n, 1.0f);
        uint r = (uint)f2bf(a0 * iv) | ((uint)f2bf(a1 * iv) << 16);
        *(uint*)&out[(size_t)node * sout + 2 * c] = r;
    }
}

__global__ __launch_bounds__(256) void gather128_k(const int* __restrict__ fillc,
                                                   const ushort* __restrict__ ell,
                                                   const ushort* __restrict__ in, int sin,
                                                   ushort* __restrict__ out, int sout) {
    int node = blockIdx.x * 4 + (threadIdx.x >> 6);
    if (node >= N_NODES) return;
    int lane = threadIdx.x & 63;
    int half = lane >> 5, c = lane & 31;      // cols {4c..4c+3}
    int n = fillc[node]; int nc = (n > ELLW) ? ELLW : n;
    const ushort* base = ell + (size_t)node * ELLW;
    float a0 = 0.f, a1 = 0.f, a2 = 0.f, a3 = 0.f;
    int i = half;
    for (; i + 2 < nc; i += 4) {
        int s0 = base[i], s1 = base[i + 2];
        uint2 u0 = *(const uint2*)&in[(size_t)s0 * sin + 4 * c];
        uint2 u1 = *(const uint2*)&in[(size_t)s1 * sin + 4 * c];
        a0 += bflo(u0.x) + bflo(u1.x);
        a1 += bfhi(u0.x) + bfhi(u1.x);
        a2 += bflo(u0.y) + bflo(u1.y);
        a3 += bfhi(u0.y) + bfhi(u1.y);
    }
    if (i < nc) {
        uint2 u0 = *(const uint2*)&in[(size_t)base[i] * sin + 4 * c];
        a0 += bflo(u0.x); a1 += bfhi(u0.x);
        a2 += bflo(u0.y); a3 += bfhi(u0.y);
    }
    a0 += __shfl_xor(a0, 32);
    a1 += __shfl_xor(a1, 32);
    a2 += __shfl_xor(a2, 32);
    a3 += __shfl_xor(a3, 32);
    if (half == 0) {
        float iv = 1.0f / fmaxf((float)n, 1.0f);
        uint2 r;
        r.x = (uint)f2bf(a0 * iv) | ((uint)f2bf(a1 * iv) << 16);
        r.y = (uint)f2bf(a2 * iv) | ((uint)f2bf(a3 * iv) << 16);
        *(uint2*)&out[(size_t)node * sout + 4 * c] = r;
    }
}

// ---------------- MFMA GEMM (layers 2/3 + h1) ----------------
// out[i, ocol+n] = relu( (A1[i,:K1] @ W1)[n] + (A2[i,:K2] @ W2)[n] + bias[n] )

template <int O, bool OUT_BF16>
__global__ __launch_bounds__(256) void mfma_gemm_k(
    const ushort* __restrict__ A1, int s1, int K1, const ushort* __restrict__ Wz1,
    const ushort* __restrict__ A2, int s2, int K2, const ushort* __restrict__ Wz2,
    const float* __restrict__ bias, void* __restrict__ outp, int so, int ocol)
{
    constexpr int NB = O / 16;
    constexpr int LDA = 40;
    __shared__ ushort ldsA[64 * LDA];

    const int tid = threadIdx.x;
    const int wave = tid >> 6, lane = tid & 63;
    const int quad = lane >> 4, l16 = lane & 15;
    const int node0 = blockIdx.x * 64;

    floatx4 acc[NB];
#pragma unroll
    for (int nb = 0; nb < NB; nb++) acc[nb] = (floatx4){0.f, 0.f, 0.f, 0.f};

#pragma unroll 1
    for (int phase = 0; phase < 2; ++phase) {
        const ushort* A = phase ? A2 : A1;
        const ushort* Wz = phase ? Wz2 : Wz1;
        const int K = phase ? K2 : K1;
        const int sA = phase ? s2 : s1;

#pragma unroll 1
        for (int k0 = 0; k0 < K; k0 += 32) {
            __syncthreads();
            {
                int row = tid >> 2, seg = tid & 3;
                int node = node0 + row;
                uint4 v = {0u, 0u, 0u, 0u};
                if (node < N_NODES)
                    v = *(const uint4*)&A[(size_t)node * sA + k0 + seg * 8];
                *(uint4*)&ldsA[row * LDA + seg * 8] = v;
            }
            __syncthreads();

            short8 a = *(const short8*)&ldsA[(wave * 16 + l16) * LDA + quad * 8];
            const short8* bz = (const short8*)Wz + (size_t)(k0 >> 5) * NB * 64;
#pragma unroll
            for (int nb = 0; nb < NB; nb++) {
                short8 b = bz[nb * 64 + lane];
                acc[nb] = __builtin_amdgcn_mfma_f32_16x16x32_bf16(a, b, acc[nb], 0, 0, 0);
            }
        }
    }

#pragma unroll
    for (int nb = 0; nb < NB; nb++) {
        int ncol = nb * 16 + l16;
        float bv = bias[ncol];
#pragma unroll
        for (int r = 0; r < 4; r++) {
            int node = node0 + wave * 16 + quad * 4 + r;
            if (node >= N_NODES) continue;
            float v = fmaxf(acc[nb][r] + bv, 0.f);
            if (OUT_BF16)
                ((ushort*)outp)[(size_t)node * so + ocol + ncol] = f2bf(v);
            else
                ((float*)outp)[(size_t)node * so + ocol + ncol] = v;
        }
    }
}

// ---------------- launch ----------------

extern "C" void kernel_launch(void* const* d_in, const int* in_sizes, int n_in,
                              void* d_out, int out_size, void* d_ws, size_t ws_size,
                              hipStream_t stream) {
    const float* x   = (const float*)d_in[0];
    const int*   ei  = (const int*)d_in[1];
    const float* Wp  = (const float*)d_in[2];
    const float* bp  = (const float*)d_in[3];
    const float* Wl1 = (const float*)d_in[4];
    const float* bl1 = (const float*)d_in[5];
    const float* Wr1 = (const float*)d_in[6];
    const float* Wl2 = (const float*)d_in[7];
    const float* bl2 = (const float*)d_in[8];
    const float* Wr2 = (const float*)d_in[9];
    const float* Wl3 = (const float*)d_in[10];
    const float* bl3 = (const float*)d_in[11];
    const float* Wr3 = (const float*)d_in[12];

    const int E = in_sizes[1] / 2;
    const int N = N_NODES;
    const int* src = ei;
    const int* dst = ei + E;

    // ---- workspace carve-up (all offsets 16B-aligned) ----
    char* p = (char*)d_ws;
    ushort* xb    = (ushort*)p;  p += (size_t)N * 64 * 2;
    ushort* feats = (ushort*)p;  p += (size_t)N * 256 * 2;
    ushort* aggx  = (ushort*)p;  p += (size_t)N * 64 * 2;
    ushort* aggf  = (ushort*)p;  p += (size_t)N * 256 * 2;
    int* fillc    = (int*)p;     p += (size_t)N * 4;
    ushort* ell   = (ushort*)p;  p += (size_t)N * ELLW * 2;
    ushort* zl1   = (ushort*)p;  p += 64 * 64 * 2;
    ushort* zr1   = (ushort*)p;  p += 64 * 64 * 2;
    ushort* zl2   = (ushort*)p;  p += 128 * 128 * 2;
    ushort* zr2   = (ushort*)p;  p += 128 * 128 * 2;
    ushort* zl3   = (ushort*)p;  p += 256 * 128 * 2;
    ushort* zr3   = (ushort*)p;  p += 256 * 128 * 2;

    hipMemsetAsync(fillc, 0, (size_t)N * sizeof(int), stream);

    const int NF = (E + 255) / 256;       // 3125 fill blocks
    const int NG = (N + 63) / 64;         // 782 gemm blocks
    const int NC = (N * 64 / 4) / 256;    // 3125 cvt blocks

    // ---- K1: fill + GEMM1(x_p) + cvt + swz, one dispatch ----
    k1_mega<<<NF + NG + NC + 52, 256, 0, stream>>>(
        src, dst, E, fillc, ell, x, xb, Wp, bp, feats,
        Wl1, zl1, Wr1, zr1, Wl2, zl2, Wr2, zr2, Wl3, zl3, Wr3, zr3,
        NF, NG, NC);

    // ---- aggx = mean-gather(xb) ----
    gather64_k<<<(N + 3) / 4, 256, 0, stream>>>(fillc, ell, xb, 64, aggx, 64);

    // ---- h1 -> feats[:,64:128] ----
    mfma_gemm_k<64, true><<<NG, 256, 0, stream>>>(
        aggx, 64, 64, zl1, xb, 64, 64, zr1, bl1, feats, 256, 64);

    // ---- aggf[:,0:128] = mean-gather(feats[:,0:128]) (layers 2 and 3) ----
    gather128_k<<<(N + 3) / 4, 256, 0, stream>>>(fillc, ell, feats, 256, aggf, 256);

    // ---- h2 -> feats[:,128:256] ----
    mfma_gemm_k<128, true><<<NG, 256, 0, stream>>>(
        aggf, 256, 128, zl2, feats, 256, 128, zr2, bl2, feats, 256, 128);

    // ---- aggf[:,128:256] = mean-gather(h2) ----
    gather128_k<<<(N + 3) / 4, 256, 0, stream>>>(fillc, ell, feats + 128, 256, aggf + 128, 256);

    // ---- h3 -> d_out (fp32) ----
    mfma_gemm_k<128, false><<<NG, 256, 0, stream>>>(
        aggf, 256, 256, zl3, feats, 256, 256, zr3, bl3, (float*)d_out, 128, 0);
}